// Round 8
// baseline (274.595 us; speedup 1.0000x reference)
//
#include <hip/hip_runtime.h>
#include <hip/hip_bf16.h>
#include <stdint.h>

#define D_MODEL 4096
#define D_BASE  8192
#define K_SUB   1024
#define N_TOK   8192

typedef __attribute__((ext_vector_type(8))) short bf16x8;
typedef __attribute__((ext_vector_type(16))) float f32x16;

__device__ __forceinline__ unsigned short f2bf(float f) {
    union { float f; uint32_t u; } c; c.f = f;
    uint32_t u = c.u;
    uint32_t r = u + 0x7FFFu + ((u >> 16) & 1u);   // round-to-nearest-even
    return (unsigned short)(r >> 16);
}

__device__ __forceinline__ void gload_lds16(const void* g, void* l) {
    __builtin_amdgcn_global_load_lds(
        (__attribute__((address_space(1))) void*)g,
        (__attribute__((address_space(3))) void*)l, 16, 0, 0);
}

#define VMCNT(N) do { __builtin_amdgcn_sched_barrier(0); \
    asm volatile("s_waitcnt vmcnt(" #N ")" ::: "memory"); } while (0)
#define PHASE_MID() do { __builtin_amdgcn_sched_barrier(0); __builtin_amdgcn_s_barrier(); \
    asm volatile("s_waitcnt lgkmcnt(0)" ::: "memory"); __builtin_amdgcn_sched_barrier(0); } while (0)
#define PHASE_END() do { __builtin_amdgcn_sched_barrier(0); __builtin_amdgcn_s_barrier(); } while (0)

// ---- prep: three massively-parallel kernels (R1-proven ~10 us for gathers) ----

// x (f32) -> xb (bf16), 8 elems/thread
__global__ void convert_x_kernel(const float* __restrict__ x, unsigned short* __restrict__ xb) {
    int t = blockIdx.x * 256 + threadIdx.x;
    const float4* p = (const float4*)x + (size_t)t * 2;
    float4 a = p[0], b = p[1];
    ushort4 lo, hi;
    lo.x = f2bf(a.x); lo.y = f2bf(a.y); lo.z = f2bf(a.z); lo.w = f2bf(a.w);
    hi.x = f2bf(b.x); hi.y = f2bf(b.y); hi.z = f2bf(b.z); hi.w = f2bf(b.w);
    *(ushort4*)(xb + (size_t)t * 8) = lo;
    *(ushort4*)(xb + (size_t)t * 8 + 4) = hi;
}

// Ut[n][k] = bf16(U[k][idx[n]]): 4M threads, coalesced writes, scatter reads
// hidden by TLP (R1 evidence: both gathers ~10 us combined).
__global__ void gather_u_kernel(const float* __restrict__ U, const int* __restrict__ idx,
                                unsigned short* __restrict__ Ut) {
    int t = blockIdx.x * 256 + threadIdx.x;
    int k = t & (D_MODEL - 1);
    int n = t >> 12;
    int col = idx[n];
    Ut[t] = f2bf(U[(size_t)k * D_BASE + col]);
}

// Vt[d][n] = bf16(V[idx[n]][d]): 4M threads, coalesced writes.
__global__ void gather_v_kernel(const float* __restrict__ V, const int* __restrict__ idx,
                                unsigned short* __restrict__ Vt) {
    int t = blockIdx.x * 256 + threadIdx.x;
    int n = t & (K_SUB - 1);
    int d = t >> 10;
    int row = idx[n];
    Vt[t] = f2bf(V[(size_t)row * D_MODEL + d]);
}

// ---------------- GEMM1: P = silu(xb @ Usub), M=8192 N=1024 K=4096 ----------------
// BM=256 BN=128 BK=64, 8 waves 4M x 2N -> wave 64x64. 32x32x16 MFMA:
// 2 m-frags x 2 n-frags x 4 k-slices = 16 MFMA/tile/wave, 16 ds_read_b128.
// 4 phases / 2 K-tiles; stages p0:{A1[T+1],B[T+1]} p1:{A0[T+2]} p2:{A1[T+2],B[T+2]}
// p3:{A0[T+3]}; waits end-p1 vmcnt(2) (0 at tail), end-p3 vmcnt(2). (R6/R7-proven)
__global__ __launch_bounds__(512, 2)
void gemm1_8p(const unsigned short* __restrict__ A, const unsigned short* __restrict__ Bt,
              unsigned short* __restrict__ C) {
    constexpr int K = D_MODEL, N = K_SUB, NT = K / 64;   // NT=64
    __shared__ __align__(16) unsigned short lds[49152];  // 96 KB

    const int t = threadIdx.x, lane = t & 63, w = t >> 6;
    const int wm = w >> 1, wn = w & 1;
    const int l31 = lane & 31, lh = lane >> 5;

    const int f = blockIdx.x;
    const int g = (f & 7) * 32 + (f >> 3);
    const int m0 = (g >> 3) * 256, n0 = (g & 7) * 128;

    const int srow = lane >> 3;
    const int scol = ((lane & 7) ^ srow) * 8;

    auto stage_A = [&](int kt, int half) {
        const unsigned short* src = A + (size_t)(m0 + half * 128) * K + kt * 64;
        unsigned short* dst = &lds[(kt & 1) * 24576 + half * 8192];
        #pragma unroll
        for (int i = 0; i < 2; ++i) {
            int c2 = i * 8 + w;
            gload_lds16(src + (size_t)(c2 * 8 + srow) * K + scol, dst + c2 * 512);
        }
    };
    auto stage_B = [&](int kt) {
        const unsigned short* src = Bt + (size_t)n0 * K + kt * 64;
        unsigned short* dst = &lds[(kt & 1) * 24576 + 16384];
        #pragma unroll
        for (int i = 0; i < 2; ++i) {
            int c2 = i * 8 + w;
            gload_lds16(src + (size_t)(c2 * 8 + srow) * K + scol, dst + c2 * 512);
        }
    };
    auto read_A = [&](int kt, bf16x8 (&af)[2][4]) {       // [mf][ks16]
        const unsigned short* base = &lds[(kt & 1) * 24576 + (wm >> 1) * 8192];
        #pragma unroll
        for (int mf = 0; mf < 2; ++mf) {
            int rw = (wm & 1) * 64 + mf * 32 + l31;
            #pragma unroll
            for (int ks = 0; ks < 4; ++ks) {
                int gg = ks * 2 + lh;
                af[mf][ks] = *(const bf16x8*)(base + rw * 64 + ((gg ^ (rw & 7)) * 8));
            }
        }
    };
    auto read_B1 = [&](int kt, int nf, bf16x8 (&bfr)[4]) {
        const unsigned short* base = &lds[(kt & 1) * 24576 + 16384];
        int rw = wn * 64 + nf * 32 + l31;
        #pragma unroll
        for (int ks = 0; ks < 4; ++ks) {
            int gg = ks * 2 + lh;
            bfr[ks] = *(const bf16x8*)(base + rw * 64 + ((gg ^ (rw & 7)) * 8));
        }
    };

    f32x16 acc[2][2] = {};   // [mf][nf]

    stage_A(0, 0); stage_A(0, 1); stage_B(0); stage_A(1, 0);
    VMCNT(2);
    __builtin_amdgcn_s_barrier();
    __builtin_amdgcn_sched_barrier(0);

    for (int kt = 0; kt < NT; kt += 2) {
        const bool more = (kt + 2 < NT);
        {   // p0: tile kt, n-frag 0
            bf16x8 af[2][4], bfr[4];
            read_A(kt, af); read_B1(kt, 0, bfr);
            stage_A(kt + 1, 1); stage_B(kt + 1);
            PHASE_MID();
            __builtin_amdgcn_s_setprio(1);
            #pragma unroll
            for (int mf = 0; mf < 2; ++mf)
                #pragma unroll
                for (int ks = 0; ks < 4; ++ks)
                    acc[mf][0] = __builtin_amdgcn_mfma_f32_32x32x16_bf16(
                        af[mf][ks], bfr[ks], acc[mf][0], 0, 0, 0);
            __builtin_amdgcn_s_setprio(0);
            PHASE_END();
            // p1: tile kt, n-frag 1 (af reused)
            bf16x8 bfr2[4];
            read_B1(kt, 1, bfr2);
            if (more) stage_A(kt + 2, 0);
            PHASE_MID();
            __builtin_amdgcn_s_setprio(1);
            #pragma unroll
            for (int mf = 0; mf < 2; ++mf)
                #pragma unroll
                for (int ks = 0; ks < 4; ++ks)
                    acc[mf][1] = __builtin_amdgcn_mfma_f32_32x32x16_bf16(
                        af[mf][ks], bfr2[ks], acc[mf][1], 0, 0, 0);
            __builtin_amdgcn_s_setprio(0);
            if (more) { VMCNT(2); } else { VMCNT(0); }
            PHASE_END();
        }
        {   // p2: tile kt+1, n-frag 0
            bf16x8 af[2][4], bfr[4];
            read_A(kt + 1, af); read_B1(kt + 1, 0, bfr);
            if (more) { stage_A(kt + 2, 1); stage_B(kt + 2); }
            PHASE_MID();
            __builtin_amdgcn_s_setprio(1);
            #pragma unroll
            for (int mf = 0; mf < 2; ++mf)
                #pragma unroll
                for (int ks = 0; ks < 4; ++ks)
                    acc[mf][0] = __builtin_amdgcn_mfma_f32_32x32x16_bf16(
                        af[mf][ks], bfr[ks], acc[mf][0], 0, 0, 0);
            __builtin_amdgcn_s_setprio(0);
            PHASE_END();
            // p3: tile kt+1, n-frag 1
            bf16x8 bfr2[4];
            read_B1(kt + 1, 1, bfr2);
            if (more) stage_A(kt + 3, 0);
            PHASE_MID();
            __builtin_amdgcn_s_setprio(1);
            #pragma unroll
            for (int mf = 0; mf < 2; ++mf)
                #pragma unroll
                for (int ks = 0; ks < 4; ++ks)
                    acc[mf][1] = __builtin_amdgcn_mfma_f32_32x32x16_bf16(
                        af[mf][ks], bfr2[ks], acc[mf][1], 0, 0, 0);
            __builtin_amdgcn_s_setprio(0);
            if (more) VMCNT(2);
            PHASE_END();
        }
    }

    // epilogue: 32x32 C layout: col=lane&31, row=(j&3)+8*(j>>2)+4*(lane>>5)
    #pragma unroll
    for (int mf = 0; mf < 2; ++mf)
        #pragma unroll
        for (int nf = 0; nf < 2; ++nf)
            #pragma unroll
            for (int j = 0; j < 16; ++j) {
                int row = m0 + wm * 64 + mf * 32 + (j & 3) + 8 * (j >> 2) + 4 * lh;
                int col = n0 + wn * 64 + nf * 32 + l31;
                float v = acc[mf][nf][j];
                v = v / (1.0f + __expf(-v));
                C[(size_t)row * N + col] = f2bf(v);
            }
}

// ---------------- GEMM2: out = P @ Vsub, M=8192 N=4096 K=1024 ----------------
// 256x256, 8 waves 2M x 4N -> wave 128x64. 32x32x16 MFMA: per quadrant (mh,nh):
// 2 m-frags x 1 n-frag x 4 k = 8 MFMA. R4-proven 4-quadrant schedule/ledger.
__global__ __launch_bounds__(512, 2)
void gemm2_8p(const unsigned short* __restrict__ A, const unsigned short* __restrict__ Bt,
              float* __restrict__ C) {
    constexpr int K = K_SUB, N = D_MODEL, NT = K / 64;   // NT=16
    constexpr int BUFSZ = 32768;
    __shared__ __align__(16) unsigned short lds[2 * BUFSZ];   // 128 KB

    const int t = threadIdx.x, lane = t & 63, w = t >> 6;
    const int wr = w >> 2, wc = w & 3;
    const int l31 = lane & 31, lh = lane >> 5;

    const int f = blockIdx.x;
    const int g = (f & 7) * 64 + (f >> 3);
    const int m0 = (g >> 4) * 256, n0 = (g & 15) * 256;

    const int srow = lane >> 3;
    const int scol = ((lane & 7) ^ srow) * 8;

    auto stage_A = [&](int kt, int mh) {
        const unsigned short* src = A + (size_t)(m0 + mh * 128) * K + kt * 64;
        unsigned short* dst = &lds[(kt & 1) * BUFSZ + mh * 8192];
        #pragma unroll
        for (int i = 0; i < 2; ++i) {
            int c2 = i * 8 + w;
            gload_lds16(src + (size_t)(c2 * 8 + srow) * K + scol, dst + c2 * 512);
        }
    };
    auto stage_B = [&](int kt, int nh) {
        const unsigned short* src = Bt + (size_t)(n0 + nh * 128) * K + kt * 64;
        unsigned short* dst = &lds[(kt & 1) * BUFSZ + 16384 + nh * 8192];
        #pragma unroll
        for (int i = 0; i < 2; ++i) {
            int c2 = i * 8 + w;
            gload_lds16(src + (size_t)(c2 * 8 + srow) * K + scol, dst + c2 * 512);
        }
    };
    auto read_A = [&](int kt, int mh, bf16x8 (&af)[2][4]) {
        const unsigned short* base = &lds[(kt & 1) * BUFSZ + mh * 8192];
        #pragma unroll
        for (int mf = 0; mf < 2; ++mf) {
            int rw = wr * 64 + mf * 32 + l31;
            #pragma unroll
            for (int ks = 0; ks < 4; ++ks) {
                int gg = ks * 2 + lh;
                af[mf][ks] = *(const bf16x8*)(base + rw * 64 + ((gg ^ (rw & 7)) * 8));
            }
        }
    };
    auto read_B = [&](int kt, int nh, bf16x8 (&bfr)[4]) {
        const unsigned short* base = &lds[(kt & 1) * BUFSZ + 16384 + nh * 8192];
        int rw = wc * 32 + l31;
        #pragma unroll
        for (int ks = 0; ks < 4; ++ks) {
            int gg = ks * 2 + lh;
            bfr[ks] = *(const bf16x8*)(base + rw * 64 + ((gg ^ (rw & 7)) * 8));
        }
    };

    f32x16 acc00[2] = {}, acc01[2] = {}, acc10[2] = {}, acc11[2] = {};

    stage_A(0, 0); stage_B(0, 0); stage_B(0, 1); stage_A(0, 1);
    stage_A(1, 0); stage_B(1, 1); stage_A(1, 1);
    VMCNT(6);
    __builtin_amdgcn_s_barrier();
    __builtin_amdgcn_sched_barrier(0);

    for (int kt = 0; kt < NT; ++kt) {
        bf16x8 af[2][4], bf0[4], bf1[4];
        {   // p0: quadrant (0,0)
            read_A(kt, 0, af); read_B(kt, 0, bf0);
            if (kt + 1 < NT) stage_B(kt + 1, 0);
            PHASE_MID();
            __builtin_amdgcn_s_setprio(1);
            #pragma unroll
            for (int mf = 0; mf < 2; ++mf)
                #pragma unroll
                for (int ks = 0; ks < 4; ++ks)
                    acc00[mf] = __builtin_amdgcn_mfma_f32_32x32x16_bf16(
                        af[mf][ks], bf0[ks], acc00[mf], 0, 0, 0);
            __builtin_amdgcn_s_setprio(0);
            PHASE_END();
        }
        {   // p1: quadrant (0,1)
            read_B(kt, 1, bf1);
            if (kt + 2 < NT) stage_A(kt + 2, 0);
            PHASE_MID();
            __builtin_amdgcn_s_setprio(1);
            #pragma unroll
            for (int mf = 0; mf < 2; ++mf)
                #pragma unroll
                for (int ks = 0; ks < 4; ++ks)
                    acc01[mf] = __builtin_amdgcn_mfma_f32_32x32x16_bf16(
                        af[mf][ks], bf1[ks], acc01[mf], 0, 0, 0);
            __builtin_amdgcn_s_setprio(0);
            PHASE_END();
        }
        {   // p2: quadrant (1,0)
            read_A(kt, 1, af);
            if (kt + 2 < NT) stage_B(kt + 2, 1);
            PHASE_MID();
            __builtin_amdgcn_s_setprio(1);
            #pragma unroll
            for (int mf = 0; mf < 2; ++mf)
                #pragma unroll
                for (int ks = 0; ks < 4; ++ks)
                    acc10[mf] = __builtin_amdgcn_mfma_f32_32x32x16_bf16(
                        af[mf][ks], bf0[ks], acc10[mf], 0, 0, 0);
            __builtin_amdgcn_s_setprio(0);
            PHASE_END();
        }
        {   // p3: quadrant (1,1)
            if (kt + 2 < NT) stage_A(kt + 2, 1);
            PHASE_MID();
            __builtin_amdgcn_s_setprio(1);
            #pragma unroll
            for (int mf = 0; mf < 2; ++mf)
                #pragma unroll
                for (int ks = 0; ks < 4; ++ks)
                    acc11[mf] = __builtin_amdgcn_mfma_f32_32x32x16_bf16(
                        af[mf][ks], bf1[ks], acc11[mf], 0, 0, 0);
            __builtin_amdgcn_s_setprio(0);
            __builtin_amdgcn_sched_barrier(0);
            if (kt < NT - 2) { VMCNT(6); }
            else if (kt == NT - 2) { VMCNT(0); }
            PHASE_END();
        }
    }

    #pragma unroll
    for (int mf = 0; mf < 2; ++mf)
        #pragma unroll
        for (int j = 0; j < 16; ++j) {
            int rbase = (j & 3) + 8 * (j >> 2) + 4 * lh + mf * 32 + wr * 64;
            int cbase = wc * 32 + l31;
            C[(size_t)(m0 + rbase) * N + (n0 + cbase)]             = acc00[mf][j];
            C[(size_t)(m0 + rbase) * N + (n0 + 128 + cbase)]       = acc01[mf][j];
            C[(size_t)(m0 + 128 + rbase) * N + (n0 + cbase)]       = acc10[mf][j];
            C[(size_t)(m0 + 128 + rbase) * N + (n0 + 128 + cbase)] = acc11[mf][j];
        }
}

extern "C" void kernel_launch(void* const* d_in, const int* in_sizes, int n_in,
                              void* d_out, int out_size, void* d_ws, size_t ws_size,
                              hipStream_t stream) {
    const float* x   = (const float*)d_in[0];
    const int*   idx = (const int*)d_in[1];
    const float* U   = (const float*)d_in[2];
    const float* V   = (const float*)d_in[3];
    float* out = (float*)d_out;

    unsigned short* Ut = (unsigned short*)d_ws;                 // [K_SUB][D_MODEL] bf16
    unsigned short* Vt = Ut + (size_t)K_SUB * D_MODEL;          // [D_MODEL][K_SUB] bf16
    unsigned short* P  = Vt + (size_t)K_SUB * D_MODEL;          // [N_TOK][K_SUB]  bf16
    unsigned short* xb = (unsigned short*)d_out;                // [N_TOK][D_MODEL] bf16 (temp)

    convert_x_kernel<<<(N_TOK * D_MODEL) / (256 * 8), 256, 0, stream>>>(x, xb);
    gather_u_kernel<<<(K_SUB * D_MODEL) / 256, 256, 0, stream>>>(U, idx, Ut);
    gather_v_kernel<<<(D_MODEL * K_SUB) / 256, 256, 0, stream>>>(V, idx, Vt);

    gemm1_8p<<<256, 512, 0, stream>>>(xb, Ut, P);
    gemm2_8p<<<512, 512, 0, stream>>>(P, Vt, out);
}

// Round 9
// 225.860 us; speedup vs baseline: 1.2158x; 1.2158x over previous
//
#include <hip/hip_runtime.h>
#include <hip/hip_bf16.h>
#include <stdint.h>

#define D_MODEL 4096
#define D_BASE  8192
#define K_SUB   1024
#define N_TOK   8192

typedef __attribute__((ext_vector_type(8))) short bf16x8;
typedef __attribute__((ext_vector_type(4))) float f32x4;

__device__ __forceinline__ unsigned short f2bf(float f) {
    union { float f; uint32_t u; } c; c.f = f;
    uint32_t u = c.u;
    uint32_t r = u + 0x7FFFu + ((u >> 16) & 1u);   // round-to-nearest-even
    return (unsigned short)(r >> 16);
}

__device__ __forceinline__ void gload_lds16(const void* g, void* l) {
    __builtin_amdgcn_global_load_lds(
        (__attribute__((address_space(1))) void*)g,
        (__attribute__((address_space(3))) void*)l, 16, 0, 0);
}

#define VMCNT(N) do { __builtin_amdgcn_sched_barrier(0); \
    asm volatile("s_waitcnt vmcnt(" #N ")" ::: "memory"); } while (0)
#define PHASE_MID() do { __builtin_amdgcn_sched_barrier(0); __builtin_amdgcn_s_barrier(); \
    asm volatile("s_waitcnt lgkmcnt(0)" ::: "memory"); __builtin_amdgcn_sched_barrier(0); } while (0)
#define PHASE_END() do { __builtin_amdgcn_sched_barrier(0); __builtin_amdgcn_s_barrier(); } while (0)

// ---------------- Fused prep (one kernel, 3 block ranges) ----------------
// b in [0,512):      gather_u — 8 k-rows x 1024 n per block, row-major reads
//                    (L2 line-dedup within each 32KB U-row: ~116 MB total vs
//                    268 MB flat), LDS transpose, 16B-run writes (4x amp, 32MB).
// b in [512,1536):   gather_v — 64x64 LDS transpose (R6-proven form).
// b in [1536,17920): convert_x — f32->bf16 stream, floods the tail so the
//                    gather stragglers overlap streaming instead of idling CUs.
__global__ __launch_bounds__(256) void prep_fused(const float* __restrict__ x,
                                                  const int* __restrict__ idx,
                                                  const float* __restrict__ U,
                                                  const float* __restrict__ V,
                                                  unsigned short* __restrict__ xb,
                                                  unsigned short* __restrict__ Ut,
                                                  unsigned short* __restrict__ Vt) {
    __shared__ __align__(16) char smem[24576];
    const int b = blockIdx.x;
    const int t = threadIdx.x;
    if (b < 512) {
        // ---- gather_u: k0 = b*8, tile[n][kr] stride 12 ushorts (24B, 8B-aligned) ----
        unsigned short* tile = (unsigned short*)smem;   // [1024][12]
        const int k0 = b * 8;
        #pragma unroll
        for (int c = 0; c < 4; ++c) {
            int n = c * 256 + t;
            int col = idx[n];
            const float* Ucol = U + (size_t)k0 * D_BASE + col;
            #pragma unroll
            for (int kr = 0; kr < 8; ++kr)
                tile[n * 12 + kr] = f2bf(Ucol[(size_t)kr * D_BASE]);
        }
        __syncthreads();
        #pragma unroll
        for (int c = 0; c < 4; ++c) {
            int n = c * 256 + t;
            ushort4 a = *(const ushort4*)&tile[n * 12];
            ushort4 q = *(const ushort4*)&tile[n * 12 + 4];
            *(ushort4*)(Ut + (size_t)n * D_MODEL + k0) = a;
            *(ushort4*)(Ut + (size_t)n * D_MODEL + k0 + 4) = q;
        }
    } else if (b < 1536) {
        // ---- gather_v: Vt[d][n] = bf16(V[idx[n]][d]) via 64x64 transpose ----
        unsigned short (*tile)[66] = (unsigned short(*)[66])smem;   // 64x66
        int* lidx = (int*)(smem + 64 * 66 * 2);
        const int bx = b - 512;
        const int n0 = (bx & 15) * 64;
        const int d0 = (bx >> 4) * 64;
        if (t < 64) lidx[t] = idx[n0 + t];
        __syncthreads();
        const int c = t & 63, r4 = t >> 6;
        #pragma unroll
        for (int p = 0; p < 16; ++p) {
            int nr = p * 4 + r4;
            tile[nr][c] = f2bf(V[(size_t)lidx[nr] * D_MODEL + d0 + c]);
        }
        __syncthreads();
        #pragma unroll
        for (int p = 0; p < 16; ++p) {
            int dr = p * 4 + r4;
            Vt[(size_t)(d0 + dr) * K_SUB + n0 + c] = tile[c][dr];
        }
    } else {
        // ---- convert_x ----
        const int cb = b - 1536;
        int e = cb * 256 + t;
        const float4* p = (const float4*)x + (size_t)e * 2;
        float4 a = p[0], q = p[1];
        ushort4 lo, hi;
        lo.x = f2bf(a.x); lo.y = f2bf(a.y); lo.z = f2bf(a.z); lo.w = f2bf(a.w);
        hi.x = f2bf(q.x); hi.y = f2bf(q.y); hi.z = f2bf(q.z); hi.w = f2bf(q.w);
        *(ushort4*)(xb + (size_t)e * 8) = lo;
        *(ushort4*)(xb + (size_t)e * 8 + 4) = hi;
    }
}

// ---------------- GEMM1: P = silu(xb @ Usub), M=8192 N=1024 K=4096 ----------------
// R6-proven (241.8 us total, 0 conflicts): BM=256 BN=128 BK=64, 8 waves 4M x 2N,
// 16x16x32 MFMA. 4 phases / 2 K-tiles; stages p0:{A1[T+1],B[T+1]} p1:{A0[T+2]}
// p2:{A1[T+2],B[T+2]} p3:{A0[T+3]}; waits end-p1 vmcnt(2) (0 at tail), end-p3 vmcnt(2).
__global__ __launch_bounds__(512, 2)
void gemm1_8p(const unsigned short* __restrict__ A, const unsigned short* __restrict__ Bt,
              unsigned short* __restrict__ C) {
    constexpr int K = D_MODEL, N = K_SUB, NT = K / 64;   // NT=64 (even)
    __shared__ __align__(16) unsigned short lds[49152];  // 96 KB

    const int t = threadIdx.x, lane = t & 63, w = t >> 6;
    const int wm = w >> 1, wn = w & 1;                   // 4M x 2N
    const int lr = lane & 15, lk = lane >> 4;

    const int f = blockIdx.x;
    const int g = (f & 7) * 32 + (f >> 3);
    const int m0 = (g >> 3) * 256, n0 = (g & 7) * 128;

    const int cswz0 = ((lk ^ (lr & 7)) * 8);
    const int cswz1 = (((4 + lk) ^ (lr & 7)) * 8);
    const int srow = lane >> 3;
    const int scol = ((lane & 7) ^ srow) * 8;

    auto stage_A = [&](int kt, int half) {
        const unsigned short* src = A + (size_t)(m0 + half * 128) * K + kt * 64;
        unsigned short* dst = &lds[(kt & 1) * 24576 + half * 8192];
        #pragma unroll
        for (int i = 0; i < 2; ++i) {
            int c2 = i * 8 + w;
            gload_lds16(src + (size_t)(c2 * 8 + srow) * K + scol, dst + c2 * 512);
        }
    };
    auto stage_B = [&](int kt) {
        const unsigned short* src = Bt + (size_t)n0 * K + kt * 64;
        unsigned short* dst = &lds[(kt & 1) * 24576 + 16384];
        #pragma unroll
        for (int i = 0; i < 2; ++i) {
            int c2 = i * 8 + w;
            gload_lds16(src + (size_t)(c2 * 8 + srow) * K + scol, dst + c2 * 512);
        }
    };
    auto read_A = [&](int kt, bf16x8 (&af)[4][2]) {
        const unsigned short* base = &lds[(kt & 1) * 24576 + (wm >> 1) * 8192];
        #pragma unroll
        for (int m = 0; m < 4; ++m) {
            int rw = (wm & 1) * 64 + m * 16 + lr;
            af[m][0] = *(const bf16x8*)(base + rw * 64 + cswz0);
            af[m][1] = *(const bf16x8*)(base + rw * 64 + cswz1);
        }
    };
    auto read_B2 = [&](int kt, int nh, bf16x8 (&bfr)[2][2]) {
        const unsigned short* base = &lds[(kt & 1) * 24576 + 16384];
        #pragma unroll
        for (int n = 0; n < 2; ++n) {
            int rw = wn * 64 + (nh * 2 + n) * 16 + lr;
            bfr[n][0] = *(const bf16x8*)(base + rw * 64 + cswz0);
            bfr[n][1] = *(const bf16x8*)(base + rw * 64 + cswz1);
        }
    };

    f32x4 acc[4][4] = {};

    stage_A(0, 0); stage_A(0, 1); stage_B(0); stage_A(1, 0);
    VMCNT(2);
    __builtin_amdgcn_s_barrier();
    __builtin_amdgcn_sched_barrier(0);

    for (int kt = 0; kt < NT; kt += 2) {
        const bool more = (kt + 2 < NT);
        {   // p0: tile kt, n-frags 0,1
            bf16x8 af[4][2], bfr[2][2];
            read_A(kt, af); read_B2(kt, 0, bfr);
            stage_A(kt + 1, 1); stage_B(kt + 1);
            PHASE_MID();
            __builtin_amdgcn_s_setprio(1);
            #pragma unroll
            for (int m = 0; m < 4; ++m)
                #pragma unroll
                for (int n = 0; n < 2; ++n)
                    #pragma unroll
                    for (int ks = 0; ks < 2; ++ks)
                        acc[m][n] = __builtin_amdgcn_mfma_f32_16x16x32_bf16(
                            af[m][ks], bfr[n][ks], acc[m][n], 0, 0, 0);
            __builtin_amdgcn_s_setprio(0);
            PHASE_END();
            // p1: tile kt, n-frags 2,3 (af reused)
            bf16x8 bfr2[2][2];
            read_B2(kt, 1, bfr2);
            if (more) stage_A(kt + 2, 0);
            PHASE_MID();
            __builtin_amdgcn_s_setprio(1);
            #pragma unroll
            for (int m = 0; m < 4; ++m)
                #pragma unroll
                for (int n = 0; n < 2; ++n)
                    #pragma unroll
                    for (int ks = 0; ks < 2; ++ks)
                        acc[m][2 + n] = __builtin_amdgcn_mfma_f32_16x16x32_bf16(
                            af[m][ks], bfr2[n][ks], acc[m][2 + n], 0, 0, 0);
            __builtin_amdgcn_s_setprio(0);
            if (more) { VMCNT(2); } else { VMCNT(0); }
            PHASE_END();
        }
        {   // p2: tile kt+1, n-frags 0,1
            bf16x8 af[4][2], bfr[2][2];
            read_A(kt + 1, af); read_B2(kt + 1, 0, bfr);
            if (more) { stage_A(kt + 2, 1); stage_B(kt + 2); }
            PHASE_MID();
            __builtin_amdgcn_s_setprio(1);
            #pragma unroll
            for (int m = 0; m < 4; ++m)
                #pragma unroll
                for (int n = 0; n < 2; ++n)
                    #pragma unroll
                    for (int ks = 0; ks < 2; ++ks)
                        acc[m][n] = __builtin_amdgcn_mfma_f32_16x16x32_bf16(
                            af[m][ks], bfr[n][ks], acc[m][n], 0, 0, 0);
            __builtin_amdgcn_s_setprio(0);
            PHASE_END();
            // p3: tile kt+1, n-frags 2,3
            bf16x8 bfr2[2][2];
            read_B2(kt + 1, 1, bfr2);
            if (more) stage_A(kt + 3, 0);
            PHASE_MID();
            __builtin_amdgcn_s_setprio(1);
            #pragma unroll
            for (int m = 0; m < 4; ++m)
                #pragma unroll
                for (int n = 0; n < 2; ++n)
                    #pragma unroll
                    for (int ks = 0; ks < 2; ++ks)
                        acc[m][2 + n] = __builtin_amdgcn_mfma_f32_16x16x32_bf16(
                            af[m][ks], bfr2[n][ks], acc[m][2 + n], 0, 0, 0);
            __builtin_amdgcn_s_setprio(0);
            if (more) VMCNT(2);
            PHASE_END();
        }
    }

    #pragma unroll
    for (int m = 0; m < 4; ++m)
        #pragma unroll
        for (int n = 0; n < 4; ++n)
            #pragma unroll
            for (int r = 0; r < 4; ++r) {
                int row = m0 + wm * 64 + m * 16 + lk * 4 + r;
                int col = n0 + wn * 64 + n * 16 + lr;
                float v = acc[m][n][r];
                v = v / (1.0f + __expf(-v));
                C[(size_t)row * N + col] = f2bf(v);
            }
}

// ---------------- GEMM2: out = P @ Vsub, M=8192 N=4096 K=1024 ----------------
// R6-proven 4-quadrant schedule (16 MFMA/phase), 256x256, T1 swizzle, 0 conflicts.
__global__ __launch_bounds__(512, 2)
void gemm2_8p(const unsigned short* __restrict__ A, const unsigned short* __restrict__ Bt,
              float* __restrict__ C) {
    constexpr int K = K_SUB, N = D_MODEL, NT = K / 64;   // NT=16
    constexpr int BUFSZ = 32768;
    __shared__ __align__(16) unsigned short lds[2 * BUFSZ];   // 128 KB

    const int t = threadIdx.x, lane = t & 63, w = t >> 6;
    const int wr = w >> 2, wc = w & 3;
    const int lr = lane & 15, lk = lane >> 4;

    const int f = blockIdx.x;
    const int g = (f & 7) * 64 + (f >> 3);
    const int m0 = (g >> 4) * 256, n0 = (g & 15) * 256;

    const int cswz0 = ((lk ^ (lr & 7)) * 8);
    const int cswz1 = (((4 + lk) ^ (lr & 7)) * 8);
    const int srow = lane >> 3;
    const int scol = ((lane & 7) ^ srow) * 8;

    auto stage_A = [&](int kt, int mh) {
        const unsigned short* src = A + (size_t)(m0 + mh * 128) * K + kt * 64;
        unsigned short* dst = &lds[(kt & 1) * BUFSZ + mh * 8192];
        #pragma unroll
        for (int i = 0; i < 2; ++i) {
            int c2 = i * 8 + w;
            gload_lds16(src + (size_t)(c2 * 8 + srow) * K + scol, dst + c2 * 512);
        }
    };
    auto stage_B = [&](int kt, int nh) {
        const unsigned short* src = Bt + (size_t)(n0 + nh * 128) * K + kt * 64;
        unsigned short* dst = &lds[(kt & 1) * BUFSZ + 16384 + nh * 8192];
        #pragma unroll
        for (int i = 0; i < 2; ++i) {
            int c2 = i * 8 + w;
            gload_lds16(src + (size_t)(c2 * 8 + srow) * K + scol, dst + c2 * 512);
        }
    };
    auto read_A = [&](int kt, int mh, bf16x8 (&af)[4][2]) {
        const unsigned short* base = &lds[(kt & 1) * BUFSZ + mh * 8192];
        #pragma unroll
        for (int m = 0; m < 4; ++m) {
            int rw = wr * 64 + m * 16 + lr;
            af[m][0] = *(const bf16x8*)(base + rw * 64 + cswz0);
            af[m][1] = *(const bf16x8*)(base + rw * 64 + cswz1);
        }
    };
    auto read_B = [&](int kt, int nh, bf16x8 (&bfr)[2][2]) {
        const unsigned short* base = &lds[(kt & 1) * BUFSZ + 16384 + nh * 8192];
        #pragma unroll
        for (int n = 0; n < 2; ++n) {
            int rw = wc * 32 + n * 16 + lr;
            bfr[n][0] = *(const bf16x8*)(base + rw * 64 + cswz0);
            bfr[n][1] = *(const bf16x8*)(base + rw * 64 + cswz1);
        }
    };

    f32x4 acc[8][4] = {};

    stage_A(0, 0); stage_B(0, 0); stage_B(0, 1); stage_A(0, 1);
    stage_A(1, 0); stage_B(1, 1); stage_A(1, 1);
    VMCNT(6);
    __builtin_amdgcn_s_barrier();
    __builtin_amdgcn_sched_barrier(0);

    for (int kt = 0; kt < NT; ++kt) {
        bf16x8 af[4][2], bf0[2][2], bf1[2][2];
        {   // p0: quadrant (0,0)
            read_A(kt, 0, af); read_B(kt, 0, bf0);
            if (kt + 1 < NT) stage_B(kt + 1, 0);
            PHASE_MID();
            __builtin_amdgcn_s_setprio(1);
            #pragma unroll
            for (int m = 0; m < 4; ++m)
                #pragma unroll
                for (int n = 0; n < 2; ++n)
                    #pragma unroll
                    for (int ks = 0; ks < 2; ++ks)
                        acc[m][n] = __builtin_amdgcn_mfma_f32_16x16x32_bf16(
                            af[m][ks], bf0[n][ks], acc[m][n], 0, 0, 0);
            __builtin_amdgcn_s_setprio(0);
            PHASE_END();
        }
        {   // p1: quadrant (0,1)
            read_B(kt, 1, bf1);
            if (kt + 2 < NT) stage_A(kt + 2, 0);
            PHASE_MID();
            __builtin_amdgcn_s_setprio(1);
            #pragma unroll
            for (int m = 0; m < 4; ++m)
                #pragma unroll
                for (int n = 0; n < 2; ++n)
                    #pragma unroll
                    for (int ks = 0; ks < 2; ++ks)
                        acc[m][2 + n] = __builtin_amdgcn_mfma_f32_16x16x32_bf16(
                            af[m][ks], bf1[n][ks], acc[m][2 + n], 0, 0, 0);
            __builtin_amdgcn_s_setprio(0);
            PHASE_END();
        }
        {   // p2: quadrant (1,0)
            read_A(kt, 1, af);
            if (kt + 2 < NT) stage_B(kt + 2, 1);
            PHASE_MID();
            __builtin_amdgcn_s_setprio(1);
            #pragma unroll
            for (int m = 0; m < 4; ++m)
                #pragma unroll
                for (int n = 0; n < 2; ++n)
                    #pragma unroll
                    for (int ks = 0; ks < 2; ++ks)
                        acc[4 + m][n] = __builtin_amdgcn_mfma_f32_16x16x32_bf16(
                            af[m][ks], bf0[n][ks], acc[4 + m][n], 0, 0, 0);
            __builtin_amdgcn_s_setprio(0);
            PHASE_END();
        }
        {   // p3: quadrant (1,1)
            if (kt + 2 < NT) stage_A(kt + 2, 1);
            PHASE_MID();
            __builtin_amdgcn_s_setprio(1);
            #pragma unroll
            for (int m = 0; m < 4; ++m)
                #pragma unroll
                for (int n = 0; n < 2; ++n)
                    #pragma unroll
                    for (int ks = 0; ks < 2; ++ks)
                        acc[4 + m][2 + n] = __builtin_amdgcn_mfma_f32_16x16x32_bf16(
                            af[m][ks], bf1[n][ks], acc[4 + m][2 + n], 0, 0, 0);
            __builtin_amdgcn_s_setprio(0);
            __builtin_amdgcn_sched_barrier(0);
            if (kt < NT - 2) { VMCNT(6); }
            else if (kt == NT - 2) { VMCNT(0); }
            PHASE_END();
        }
    }

    #pragma unroll
    for (int mh = 0; mh < 2; ++mh)
        #pragma unroll
        for (int nh = 0; nh < 2; ++nh)
            #pragma unroll
            for (int m = 0; m < 4; ++m)
                #pragma unroll
                for (int n = 0; n < 2; ++n)
                    #pragma unroll
                    for (int r = 0; r < 4; ++r) {
                        int row = m0 + mh * 128 + wr * 64 + m * 16 + lk * 4 + r;
                        int col = n0 + nh * 128 + wc * 32 + n * 16 + lr;
                        C[(size_t)row * N + col] = acc[mh * 4 + m][nh * 2 + n][r];
                    }
}

extern "C" void kernel_launch(void* const* d_in, const int* in_sizes, int n_in,
                              void* d_out, int out_size, void* d_ws, size_t ws_size,
                              hipStream_t stream) {
    const float* x   = (const float*)d_in[0];
    const int*   idx = (const int*)d_in[1];
    const float* U   = (const float*)d_in[2];
    const float* V   = (const float*)d_in[3];
    float* out = (float*)d_out;

    unsigned short* Ut = (unsigned short*)d_ws;                 // [K_SUB][D_MODEL] bf16
    unsigned short* Vt = Ut + (size_t)K_SUB * D_MODEL;          // [D_MODEL][K_SUB] bf16
    unsigned short* P  = Vt + (size_t)K_SUB * D_MODEL;          // [N_TOK][K_SUB]  bf16
    unsigned short* xb = (unsigned short*)d_out;                // [N_TOK][D_MODEL] bf16 (temp)

    prep_fused<<<512 + 1024 + 16384, 256, 0, stream>>>(x, idx, U, V, xb, Ut, Vt);
    gemm1_8p<<<256, 512, 0, stream>>>(xb, Ut, P);
    gemm2_8p<<<512, 512, 0, stream>>>(P, Vt, out);
}